// Round 6
// baseline (128.836 us; speedup 1.0000x reference)
//
#include <hip/hip_runtime.h>

#define NN 2048

typedef unsigned short u16;
typedef __attribute__((ext_vector_type(8))) short short8;
typedef __attribute__((ext_vector_type(4))) float floatx4;

__device__ __forceinline__ u16 f2bf(float f) {
  unsigned u = __float_as_uint(f);
  u += 0x7FFF + ((u >> 16) & 1);   // RNE
  return (u16)(u >> 16);
}

__device__ __forceinline__ float bf2f(u16 h) {
  return __uint_as_float(((unsigned)h) << 16);
}

// async global->LDS, 16B per lane. LDS dest = wave-uniform base + lane*16.
__device__ __forceinline__ void load_lds16(const u16* g, u16* l) {
  __builtin_amdgcn_global_load_lds(
      (const __attribute__((address_space(1))) unsigned int*)g,
      (__attribute__((address_space(3))) unsigned int*)l,
      16, 0, 0);
}

// ---------------------------------------------------------------------------
// prep v3: fp32 -> bf16 (Abf row-major + AbfT transposed), fp32 row-sum
// partials degp[mat][row][32], zero tri.
// Thread (q = t>>4, cs = t&15) owns the 4x4 block rows 4q..4q+3, cols
// 4cs..4cs+3 of the 64x64 tile. Reads 4 coalesced float4 (lanes cs-fastest ->
// 256B segments), converts, TRANSPOSES 4x4 IN REGISTERS, then:
//   - Abf: 4 x 8B row-major stores (32B contiguous per 4-lane group)
//   - LDS: 4 x ds_write_b64 at Tl[(4cs+e)*17 + q] (ushort4 units, pitch 17
//     -> <=4-way on dword0, vs prep v2's 16 scalar writes at ~16-way)
// Phase 2: 2 x ds_read_b64 (<=2-way) + one 16B coalesced AbfT store.
// grid (32,32,2), block 256.
// ---------------------------------------------------------------------------
__global__ __launch_bounds__(256) void prep_kernel(
    const float* __restrict__ A1, const float* __restrict__ A2,
    u16* __restrict__ Abf, u16* __restrict__ AbfT,
    float* __restrict__ degp, float* __restrict__ tri) {
  __shared__ u16 Tl[64 * 17 * 4];  // [row' 0..63][chunk 0..16] ushort4 units
  const int bx = blockIdx.x, by = blockIdx.y, bz = blockIdx.z;
  const float* __restrict__ A = bz ? A2 : A1;
  u16* __restrict__ ab = Abf + (size_t)bz * (NN * (size_t)NN);
  u16* __restrict__ at = AbfT + (size_t)bz * (NN * (size_t)NN);
  float* __restrict__ dp = degp + (size_t)bz * (32 * NN);
  const int t = threadIdx.x;
  const int r0 = by * 64, c0 = bx * 64;
  const int q = t >> 4, cs = t & 15;

  if (bx == 0 && t < 64) tri[bz * NN + by * 64 + t] = 0.f;

  u16 m[4][4];
#pragma unroll
  for (int d = 0; d < 4; ++d) {
    const int r = 4 * q + d;
    const float4 fv = *(const float4*)(A + (size_t)(r0 + r) * NN + c0 + cs * 4);
    ushort4 b;
    b.x = f2bf(fv.x); b.y = f2bf(fv.y); b.z = f2bf(fv.z); b.w = f2bf(fv.w);
    *(ushort4*)(ab + (size_t)(r0 + r) * NN + c0 + cs * 4) = b;
    m[d][0] = b.x; m[d][1] = b.y; m[d][2] = b.z; m[d][3] = b.w;
    // row-sum partial: reduce across cs (contiguous 16 lanes in-wave)
    float s = fv.x + fv.y + fv.z + fv.w;
    s += __shfl_xor(s, 1); s += __shfl_xor(s, 2);
    s += __shfl_xor(s, 4); s += __shfl_xor(s, 8);
    if (cs == 0) dp[(size_t)(r0 + r) * 32 + bx] = s;
  }
  // register transpose: column e of m -> ushort4 along source rows
#pragma unroll
  for (int e = 0; e < 4; ++e) {
    ushort4 tc;
    tc.x = m[0][e]; tc.y = m[1][e]; tc.z = m[2][e]; tc.w = m[3][e];
    *(ushort4*)(Tl + ((4 * cs + e) * 17 + q) * 4) = tc;
  }
  __syncthreads();
  // gather: thread (row' = p*32 + (t>>3), mm = t&7) -> u16 span [8mm, 8mm+8)
#pragma unroll
  for (int p = 0; p < 2; ++p) {
    const int rp = p * 32 + (t >> 3);
    const int mm = t & 7;
    const ushort4 v0 = *(const ushort4*)(Tl + (rp * 17 + 2 * mm) * 4);
    const ushort4 v1 = *(const ushort4*)(Tl + (rp * 17 + 2 * mm + 1) * 4);
    ushort4* dst = (ushort4*)(at + (size_t)(c0 + rp) * NN + r0 + mm * 8);
    dst[0] = v0;
    dst[1] = v1;
  }
}

#define MFMA_BODY(PB)                                                     \
  {                                                                       \
    short8 af[4], bfr[4];                                                 \
    _Pragma("unroll")                                                     \
    for (int tm = 0; tm < 4; ++tm)                                        \
      af[tm] = *(const short8*)(smem + (PB) + aoff[tm]);                  \
    _Pragma("unroll")                                                     \
    for (int tn = 0; tn < 4; ++tn)                                        \
      bfr[tn] = *(const short8*)(smem + (PB) + boff[tn]);                 \
    _Pragma("unroll")                                                     \
    for (int tm = 0; tm < 4; ++tm)                                        \
      _Pragma("unroll")                                                   \
      for (int tn = 0; tn < 4; ++tn)                                      \
        acc[tm][tn] = __builtin_amdgcn_mfma_f32_16x16x32_bf16(            \
            af[tm], bfr[tn], acc[tm][tn], 0, 0, 0);                       \
  }

#define PREFETCH(KK, DB)                                                  \
  load_lds16(gA0 + (KK), smem + (DB) + sA0);                              \
  load_lds16(gA1 + (KK), smem + (DB) + sA1);                              \
  load_lds16(gB0 + (KK), smem + (DB) + sB0);                              \
  load_lds16(gB1 + (KK), smem + (DB) + sB1);

#define FENCE asm volatile("" ::: "memory")

// ---------------------------------------------------------------------------
// gemm_tri (R4 config — best measured: 49.7 us, VGPR 64, Occ 31%):
// tri[i] += sum_j (A@A)_{ij} * A_{ji}, fused. Split-K=2 (z = mat*2 + kz).
// 128x128 C-tile, BK=32, 4 waves, 16x16x32 MFMA, double-buffered LDS with
// raw s_barrier + vmcnt(4). VGPR(64) + AGPR(64) = 128 -> 4 waves/SIMD class,
// LDS 34816 -> 4 blocks/CU co-resident.
// grid (16,16,4), block 256.
// ---------------------------------------------------------------------------
__global__ __launch_bounds__(256, 4) void gemm_tri_kernel(
    const u16* __restrict__ Abf, const u16* __restrict__ AbfT,
    float* __restrict__ tri) {
  // loop: buf0 [0,8192) u16, buf1 [8192,16384); each buf: As 4096 + Bs 4096.
  // epilogue reuses [0,17408) as T 128x136.
  __shared__ u16 smem[17408];

  const int tid = threadIdx.x;
  const int w = tid >> 6, lane = tid & 63;
  const int wm = w >> 1, wn = w & 1;
  const int cl = lane & 15, g = lane >> 4;
  const int i0 = blockIdx.y * 128, j0 = blockIdx.x * 128;
  const int mz = blockIdx.z >> 1, kz = blockIdx.z & 1;
  const size_t mat = (size_t)mz * (NN * (size_t)NN);
  const u16* __restrict__ Am = Abf + mat;
  const u16* __restrict__ ATm = AbfT + mat;
  float* __restrict__ triM = tri + mz * NN;

  // staging: wave w stages 2 row-slices for As, 2 for Bs per K-step.
  // LDS slot s (16B) -> row = s>>2, stored chunk c' = s&3 holds global chunk
  // c = c' ^ ((row>>1)&3)  (global-side XOR swizzle -> frag reads conflict-free)
  const int s0 = (w * 2 + 0) * 64 + lane;
  const int s1 = (w * 2 + 1) * 64 + lane;
  const int r0s = s0 >> 2, c0s = (s0 & 3) ^ ((r0s >> 1) & 3);
  const int r1s = s1 >> 2, c1s = (s1 & 3) ^ ((r1s >> 1) & 3);
  const int kbase = kz * 1024;
  const u16* gA0 = Am + (size_t)(i0 + r0s) * NN + kbase + c0s * 8;
  const u16* gA1 = Am + (size_t)(i0 + r1s) * NN + kbase + c1s * 8;
  const u16* gB0 = ATm + (size_t)(j0 + r0s) * NN + kbase + c0s * 8;
  const u16* gB1 = ATm + (size_t)(j0 + r1s) * NN + kbase + c1s * 8;
  const int sA0 = (w * 2 + 0) * 512, sA1 = (w * 2 + 1) * 512;
  const int sB0 = 4096 + sA0, sB1 = 4096 + sA1;

  // fragment read offsets (u16 elements) within a buffer
  const int swz = g ^ ((cl >> 1) & 3);
  int aoff[4], boff[4];
#pragma unroll
  for (int tm = 0; tm < 4; ++tm)
    aoff[tm] = (wm * 64 + tm * 16 + cl) * 32 + swz * 8;
#pragma unroll
  for (int tn = 0; tn < 4; ++tn)
    boff[tn] = 4096 + (wn * 64 + tn * 16 + cl) * 32 + swz * 8;

  floatx4 acc[4][4] = {};

  // preamble: iter 0 -> buf 0
  PREFETCH(0, 0)

  // 15 double-steps, iters 0..29 (all with prefetch)
#pragma unroll 1
  for (int d = 0; d < 15; ++d) {
    // iter 2d: compute buf0, prefetch (2d+1) -> buf1
    FENCE; __builtin_amdgcn_s_barrier(); FENCE;
    PREFETCH((2 * d + 1) * 32, 8192)
    __builtin_amdgcn_s_waitcnt(0x0F74);  // vmcnt(4)
    FENCE; __builtin_amdgcn_s_barrier(); FENCE;
    MFMA_BODY(0)
    // iter 2d+1: compute buf1, prefetch (2d+2) -> buf0
    FENCE; __builtin_amdgcn_s_barrier(); FENCE;
    PREFETCH((2 * d + 2) * 32, 0)
    __builtin_amdgcn_s_waitcnt(0x0F74);  // vmcnt(4)
    FENCE; __builtin_amdgcn_s_barrier(); FENCE;
    MFMA_BODY(8192)
  }
  // iter 30: compute buf0, prefetch 31 -> buf1
  FENCE; __builtin_amdgcn_s_barrier(); FENCE;
  PREFETCH(31 * 32, 8192)
  __builtin_amdgcn_s_waitcnt(0x0F74);
  FENCE; __builtin_amdgcn_s_barrier(); FENCE;
  MFMA_BODY(0)
  // iter 31: compute buf1, no prefetch
  FENCE; __builtin_amdgcn_s_barrier(); FENCE;
  __builtin_amdgcn_s_waitcnt(0x0F70);  // vmcnt(0)
  FENCE; __builtin_amdgcn_s_barrier(); FENCE;
  MFMA_BODY(8192)

  // epilogue: tri[i0+r] += sum_c C[r][c] * A^T[i0+r][j0+c]
  __syncthreads();
#pragma unroll
  for (int it = 0; it < 8; ++it) {
    const int idx = tid + it * 256;
    const int r = idx >> 4, co = (idx & 15) * 8;
    *(uint4*)(smem + r * 136 + co) =
        *(const uint4*)(ATm + (size_t)(i0 + r) * NN + j0 + co);
  }
  __syncthreads();

#pragma unroll
  for (int tm = 0; tm < 4; ++tm) {
#pragma unroll
    for (int reg = 0; reg < 4; ++reg) {
      const int rloc = wm * 64 + tm * 16 + g * 4 + reg;  // C/D: row=(lane>>4)*4+reg
      float v = 0.f;
#pragma unroll
      for (int tn = 0; tn < 4; ++tn) {
        const int cloc = wn * 64 + tn * 16 + cl;          // C/D: col=lane&15
        v += acc[tm][tn][reg] * bf2f(smem[rloc * 136 + cloc]);
      }
      v += __shfl_xor(v, 1);
      v += __shfl_xor(v, 2);
      v += __shfl_xor(v, 4);
      v += __shfl_xor(v, 8);
      if (cl == 0) atomicAdd(&triM[i0 + rloc], v);
    }
  }
}

// ---------------------------------------------------------------------------
// finalize stage 1: grid 16 x 1024 threads; block b reduces rows [b*128,+128).
// ---------------------------------------------------------------------------
__global__ __launch_bounds__(1024) void finalize1_kernel(
    const float* __restrict__ degp, const float* __restrict__ tri,
    float* __restrict__ part) {
  __shared__ float red[32];
  const int t = threadIdx.x;
  const int r = blockIdx.x * 128 + (t >> 3);   // row
  const int q = (t & 7) * 4;                   // degp chunk
  const float4 v1 = *(const float4*)(degp + (size_t)r * 32 + q);
  const float4 v2 = *(const float4*)(degp + 32 * NN + (size_t)r * 32 + q);
  float d1 = v1.x + v1.y + v1.z + v1.w;
  float d2 = v2.x + v2.y + v2.z + v2.w;
#pragma unroll
  for (int m = 1; m < 8; m <<= 1) {
    d1 += __shfl_xor(d1, m);
    d2 += __shfl_xor(d2, m);
  }
  float sdd = 0.f, scc = 0.f;
  if ((t & 7) == 0) {
    const float t1 = tri[r], t2 = tri[NN + r];
    const float e1 = d1 < 2.f ? 1.f : d1;
    const float e2 = d2 < 2.f ? 1.f : d2;
    sdd = fabsf(d1 - d2);
    scc = fabsf(t1 / (e1 * (e1 - 1.f)) - t2 / (e2 * (e2 - 1.f)));
  }
#pragma unroll
  for (int m = 8; m < 64; m <<= 1) {
    sdd += __shfl_xor(sdd, m);
    scc += __shfl_xor(scc, m);
  }
  const int wv = t >> 6, ln = t & 63;
  if (ln == 0) { red[wv] = sdd; red[16 + wv] = scc; }
  __syncthreads();
  if (t == 0) {
    float a = 0.f, b = 0.f;
#pragma unroll
    for (int i = 0; i < 16; ++i) { a += red[i]; b += red[16 + i]; }
    part[blockIdx.x * 2 + 0] = a;
    part[blockIdx.x * 2 + 1] = b;
  }
}

__global__ void finalize2_kernel(const float* __restrict__ part,
                                 float* __restrict__ out) {
  if (threadIdx.x == 0) {
    float a = 0.f, b = 0.f;
#pragma unroll
    for (int i = 0; i < 16; ++i) { a += part[i * 2]; b += part[i * 2 + 1]; }
    const float ds = expf(-a * (1.f / (float)NN));
    const float cs = expf(-b * (1.f / (float)NN));
    out[0] = ds;
    out[1] = cs;
    out[2] = 0.5f * (ds + cs);
  }
}

extern "C" void kernel_launch(void* const* d_in, const int* in_sizes, int n_in,
                              void* d_out, int out_size, void* d_ws, size_t ws_size,
                              hipStream_t stream) {
  (void)in_sizes; (void)n_in; (void)out_size; (void)ws_size;
  const float* A1 = (const float*)d_in[0];
  const float* A2 = (const float*)d_in[1];
  float* out = (float*)d_out;

  // workspace layout:
  //   Abf  [2][2048*2048] u16
  //   AbfT [2][2048*2048] u16
  //   tri  [2][2048] f32
  //   degp [2][2048][32] f32
  //   part [32] f32
  u16* Abf = (u16*)d_ws;
  u16* AbfT = Abf + 2 * (size_t)NN * NN;
  float* tri = (float*)(AbfT + 2 * (size_t)NN * NN);
  float* degp = tri + 2 * NN;
  float* part = degp + 2 * 32 * NN;

  prep_kernel<<<dim3(32, 32, 2), 256, 0, stream>>>(A1, A2, Abf, AbfT, degp, tri);
  gemm_tri_kernel<<<dim3(16, 16, 4), 256, 0, stream>>>(Abf, AbfT, tri);
  finalize1_kernel<<<16, 1024, 0, stream>>>(degp, tri, part);
  finalize2_kernel<<<1, 64, 0, stream>>>(part, out);
}

// Round 7
// 115.713 us; speedup vs baseline: 1.1134x; 1.1134x over previous
//
#include <hip/hip_runtime.h>

#define NN 2048

typedef unsigned short u16;
typedef unsigned char u8;
typedef __attribute__((ext_vector_type(4))) float floatx4;

// fp8 e4m3fn (positive-only domain here) -> f32
__device__ __forceinline__ float fp8_to_f32(unsigned v) {
  const unsigned e = (v >> 3) & 15, m = v & 7;
  const float norm = __uint_as_float(((e + 120u) << 23) | (m << 20));
  const float sub = (float)m * 0.001953125f;  // m * 2^-9
  return e == 0 ? sub : norm;
}

// async global->LDS, 16B per lane. LDS dest = wave-uniform base + lane*16.
__device__ __forceinline__ void load_lds16(const u8* g, u8* l) {
  __builtin_amdgcn_global_load_lds(
      (const __attribute__((address_space(1))) unsigned int*)g,
      (__attribute__((address_space(3))) unsigned int*)l,
      16, 0, 0);
}

// ---------------------------------------------------------------------------
// prep v4: fp32 -> fp8 e4m3 (A8 row-major + A8T transposed), fp32 row-sum
// partials degp[mat][row][32], zero tri. HW cvt_pk_fp8 (RNE), 4x4 register
// transpose, uint LDS tiles (pitch 17 -> conflict-spread), coalesced stores.
// grid (32,32,2), block 256. Tile 64x64.
// ---------------------------------------------------------------------------
__global__ __launch_bounds__(256) void prep_kernel(
    const float* __restrict__ A1, const float* __restrict__ A2,
    u8* __restrict__ A8, u8* __restrict__ A8T,
    float* __restrict__ degp, float* __restrict__ tri) {
  __shared__ unsigned Tl[64 * 17];
  const int bx = blockIdx.x, by = blockIdx.y, bz = blockIdx.z;
  const float* __restrict__ A = bz ? A2 : A1;
  u8* __restrict__ ab = A8 + (size_t)bz * (NN * (size_t)NN);
  u8* __restrict__ at = A8T + (size_t)bz * (NN * (size_t)NN);
  float* __restrict__ dp = degp + (size_t)bz * (32 * NN);
  const int t = threadIdx.x;
  const int r0 = by * 64, c0 = bx * 64;
  const int q = t >> 4, cs = t & 15;

  if (bx == 0 && t < 64) tri[bz * NN + by * 64 + t] = 0.f;

  unsigned rowpack[4];
#pragma unroll
  for (int d = 0; d < 4; ++d) {
    const int r = 4 * q + d;
    const float4 fv = *(const float4*)(A + (size_t)(r0 + r) * NN + c0 + cs * 4);
    int pk = __builtin_amdgcn_cvt_pk_fp8_f32(fv.x, fv.y, 0, false);
    pk = __builtin_amdgcn_cvt_pk_fp8_f32(fv.z, fv.w, pk, true);
    rowpack[d] = (unsigned)pk;
    *(unsigned*)(ab + (size_t)(r0 + r) * NN + c0 + cs * 4) = (unsigned)pk;
    // exact fp32 row-sum partial over this 64-col slab
    float s = fv.x + fv.y + fv.z + fv.w;
    s += __shfl_xor(s, 1); s += __shfl_xor(s, 2);
    s += __shfl_xor(s, 4); s += __shfl_xor(s, 8);
    if (cs == 0) dp[(size_t)(r0 + r) * 32 + bx] = s;
  }
  // 4x4 byte transpose in registers
#pragma unroll
  for (int e = 0; e < 4; ++e) {
    const unsigned tc = ((rowpack[0] >> (8 * e)) & 0xFFu) |
                        (((rowpack[1] >> (8 * e)) & 0xFFu) << 8) |
                        (((rowpack[2] >> (8 * e)) & 0xFFu) << 16) |
                        (((rowpack[3] >> (8 * e)) & 0xFFu) << 24);
    Tl[(4 * cs + e) * 17 + q] = tc;
  }
  __syncthreads();
#pragma unroll
  for (int p = 0; p < 2; ++p) {
    const int rp = p * 32 + (t >> 3);
    const int mm = t & 7;
    uint2 v;
    v.x = Tl[rp * 17 + 2 * mm];
    v.y = Tl[rp * 17 + 2 * mm + 1];
    *(uint2*)(at + (size_t)(c0 + rp) * NN + r0 + mm * 8) = v;
  }
}

#define MFMA_BODY(PB)                                                      \
  {                                                                        \
    long aL[4][2], bL[4][2];                                               \
    _Pragma("unroll")                                                      \
    for (int tm = 0; tm < 4; ++tm) {                                       \
      aL[tm][0] = *(const long*)(smem + (PB) + aoff[tm][0]);               \
      aL[tm][1] = *(const long*)(smem + (PB) + aoff[tm][1]);               \
    }                                                                      \
    _Pragma("unroll")                                                      \
    for (int tn = 0; tn < 4; ++tn) {                                       \
      bL[tn][0] = *(const long*)(smem + (PB) + boff[tn][0]);               \
      bL[tn][1] = *(const long*)(smem + (PB) + boff[tn][1]);               \
    }                                                                      \
    _Pragma("unroll")                                                      \
    for (int tm = 0; tm < 4; ++tm)                                         \
      _Pragma("unroll")                                                    \
      for (int tn = 0; tn < 4; ++tn) {                                     \
        acc[tm][tn] = __builtin_amdgcn_mfma_f32_16x16x32_fp8_fp8(          \
            aL[tm][0], bL[tn][0], acc[tm][tn], 0, 0, 0);                   \
        acc[tm][tn] = __builtin_amdgcn_mfma_f32_16x16x32_fp8_fp8(          \
            aL[tm][1], bL[tn][1], acc[tm][tn], 0, 0, 0);                   \
      }                                                                    \
  }

#define PREFETCH(KK, DB)                                                   \
  load_lds16(gA0 + (KK), smem + (DB) + sA0);                               \
  load_lds16(gA1 + (KK), smem + (DB) + sA1);                               \
  load_lds16(gB0 + (KK), smem + (DB) + sB0);                               \
  load_lds16(gB1 + (KK), smem + (DB) + sB1);

#define FENCE asm volatile("" ::: "memory")

// ---------------------------------------------------------------------------
// gemm_tri fp8: tri[i] += sum_j (A@A)_{ij} * A_{ji}. Non-scaled fp8 MFMA runs
// at bf16 rate, but HALVES all LDS/global bytes: BK=64 at the same 16 KB per
// buffer, 16 K-steps (vs 32), LDS traffic/FLOP halved (floor ~30us -> ~15us —
// R6 analysis showed LDS bandwidth, not latency, is the binding resource).
// Same proven R4 pipeline: 2 buffers, raw s_barrier + vmcnt(4). Split-K=2.
// Chunk-XOR swizzle carries over exactly (row = 64 B in both layouts).
// Frag reads: 2 x ds_read_b64 per frag (halves: k 0..31 | 32..63), <=2-way.
// grid (16,16,4), block 256, LDS 32 KB -> 4 blocks/CU.
// ---------------------------------------------------------------------------
__global__ __launch_bounds__(256, 4) void gemm_tri_kernel(
    const u8* __restrict__ A8, const u8* __restrict__ A8T,
    float* __restrict__ tri) {
  // buf0 [0,16384): As 8 KB + Bs 8 KB; buf1 [16384,32768).
  // epilogue reuses [0, 128*144=18432) as T tile.
  __shared__ __align__(16) u8 smem[32768];

  const int tid = threadIdx.x;
  const int w = tid >> 6, lane = tid & 63;
  const int wm = w >> 1, wn = w & 1;
  const int cl = lane & 15, g = lane >> 4;
  const int i0 = blockIdx.y * 128, j0 = blockIdx.x * 128;
  const int mz = blockIdx.z >> 1, kz = blockIdx.z & 1;
  const size_t mat = (size_t)mz * (NN * (size_t)NN);
  const u8* __restrict__ Am = A8 + mat;
  const u8* __restrict__ ATm = A8T + mat;
  float* __restrict__ triM = tri + mz * NN;

  // staging: 8 KB/operand/step = 512 slots of 16 B; wave w owns slots
  // w*128 + lane and w*128+64+lane. slot s -> row = s>>2 (64 B rows),
  // stored chunk c' = s&3 holds global chunk c = c' ^ ((row>>1)&3).
  const int s0 = (w * 2 + 0) * 64 + lane;
  const int s1 = (w * 2 + 1) * 64 + lane;
  const int r0s = s0 >> 2, c0s = (s0 & 3) ^ ((r0s >> 1) & 3);
  const int r1s = s1 >> 2, c1s = (s1 & 3) ^ ((r1s >> 1) & 3);
  const int kbase = kz * 1024;  // bytes along K (split-K half)
  const u8* gA0 = Am + (size_t)(i0 + r0s) * NN + kbase + c0s * 16;
  const u8* gA1 = Am + (size_t)(i0 + r1s) * NN + kbase + c1s * 16;
  const u8* gB0 = ATm + (size_t)(j0 + r0s) * NN + kbase + c0s * 16;
  const u8* gB1 = ATm + (size_t)(j0 + r1s) * NN + kbase + c1s * 16;
  const int sA0 = (w * 2 + 0) * 1024, sA1 = (w * 2 + 1) * 1024;
  const int sB0 = 8192 + sA0, sB1 = 8192 + sA1;

  // fragment read offsets (bytes within buffer): frag row r, K-half h needs
  // bytes 32h + g*8 .. +7 -> chunk 2h + (g>>1) (XOR-swizzled), sub (g&1)*8.
  const int rsw = (cl >> 1) & 3;
  const int sub = (g & 1) * 8, ch = g >> 1;
  int aoff[4][2], boff[4][2];
#pragma unroll
  for (int tm = 0; tm < 4; ++tm) {
    const int r = wm * 64 + tm * 16 + cl;
#pragma unroll
    for (int h = 0; h < 2; ++h)
      aoff[tm][h] = r * 64 + (((2 * h + ch) ^ rsw) * 16) + sub;
  }
#pragma unroll
  for (int tn = 0; tn < 4; ++tn) {
    const int r = wn * 64 + tn * 16 + cl;
#pragma unroll
    for (int h = 0; h < 2; ++h)
      boff[tn][h] = 8192 + r * 64 + (((2 * h + ch) ^ rsw) * 16) + sub;
  }

  floatx4 acc[4][4] = {};

  // preamble: step 0 -> buf 0
  PREFETCH(0, 0)

  // 16 K-steps of BK=64 bytes; steps 0..13 in the loop
#pragma unroll 1
  for (int d = 0; d < 7; ++d) {
    // step 2d: compute buf0, prefetch 2d+1 -> buf1
    FENCE; __builtin_amdgcn_s_barrier(); FENCE;
    PREFETCH((2 * d + 1) * 64, 16384)
    __builtin_amdgcn_s_waitcnt(0x0F74);  // vmcnt(4)
    FENCE; __builtin_amdgcn_s_barrier(); FENCE;
    MFMA_BODY(0)
    // step 2d+1: compute buf1, prefetch 2d+2 -> buf0
    FENCE; __builtin_amdgcn_s_barrier(); FENCE;
    PREFETCH((2 * d + 2) * 64, 0)
    __builtin_amdgcn_s_waitcnt(0x0F74);  // vmcnt(4)
    FENCE; __builtin_amdgcn_s_barrier(); FENCE;
    MFMA_BODY(16384)
  }
  // step 14: compute buf0, prefetch 15 -> buf1
  FENCE; __builtin_amdgcn_s_barrier(); FENCE;
  PREFETCH(15 * 64, 16384)
  __builtin_amdgcn_s_waitcnt(0x0F74);
  FENCE; __builtin_amdgcn_s_barrier(); FENCE;
  MFMA_BODY(0)
  // step 15: compute buf1, drain
  FENCE; __builtin_amdgcn_s_barrier(); FENCE;
  __builtin_amdgcn_s_waitcnt(0x0F70);  // vmcnt(0)
  FENCE; __builtin_amdgcn_s_barrier(); FENCE;
  MFMA_BODY(16384)

  // epilogue: tri[i0+r] += sum_c C[r][c] * A^T[i0+r][j0+c]
  __syncthreads();
  // stage T: 128 rows x 128 B fp8, pitch 144 (16B-aligned, bank-spread)
#pragma unroll
  for (int it = 0; it < 4; ++it) {
    const int idx = tid + it * 256;
    const int r = idx >> 3, co = (idx & 7) * 16;
    *(uint4*)(smem + r * 144 + co) =
        *(const uint4*)(ATm + (size_t)(i0 + r) * NN + j0 + co);
  }
  __syncthreads();

#pragma unroll
  for (int tm = 0; tm < 4; ++tm) {
#pragma unroll
    for (int reg = 0; reg < 4; ++reg) {
      const int rloc = wm * 64 + tm * 16 + g * 4 + reg;  // C/D: row=(lane>>4)*4+reg
      float v = 0.f;
#pragma unroll
      for (int tn = 0; tn < 4; ++tn) {
        const int cloc = wn * 64 + tn * 16 + cl;          // C/D: col=lane&15
        v += acc[tm][tn][reg] * fp8_to_f32(smem[rloc * 144 + cloc]);
      }
      v += __shfl_xor(v, 1);
      v += __shfl_xor(v, 2);
      v += __shfl_xor(v, 4);
      v += __shfl_xor(v, 8);
      if (cl == 0) atomicAdd(&triM[i0 + rloc], v);
    }
  }
}

// ---------------------------------------------------------------------------
// finalize stage 1: grid 16 x 1024 threads; block b reduces rows [b*128,+128).
// ---------------------------------------------------------------------------
__global__ __launch_bounds__(1024) void finalize1_kernel(
    const float* __restrict__ degp, const float* __restrict__ tri,
    float* __restrict__ part) {
  __shared__ float red[32];
  const int t = threadIdx.x;
  const int r = blockIdx.x * 128 + (t >> 3);   // row
  const int q = (t & 7) * 4;                   // degp chunk
  const float4 v1 = *(const float4*)(degp + (size_t)r * 32 + q);
  const float4 v2 = *(const float4*)(degp + 32 * NN + (size_t)r * 32 + q);
  float d1 = v1.x + v1.y + v1.z + v1.w;
  float d2 = v2.x + v2.y + v2.z + v2.w;
#pragma unroll
  for (int m = 1; m < 8; m <<= 1) {
    d1 += __shfl_xor(d1, m);
    d2 += __shfl_xor(d2, m);
  }
  float sdd = 0.f, scc = 0.f;
  if ((t & 7) == 0) {
    const float t1 = tri[r], t2 = tri[NN + r];
    const float e1 = d1 < 2.f ? 1.f : d1;
    const float e2 = d2 < 2.f ? 1.f : d2;
    sdd = fabsf(d1 - d2);
    scc = fabsf(t1 / (e1 * (e1 - 1.f)) - t2 / (e2 * (e2 - 1.f)));
  }
#pragma unroll
  for (int m = 8; m < 64; m <<= 1) {
    sdd += __shfl_xor(sdd, m);
    scc += __shfl_xor(scc, m);
  }
  const int wv = t >> 6, ln = t & 63;
  if (ln == 0) { red[wv] = sdd; red[16 + wv] = scc; }
  __syncthreads();
  if (t == 0) {
    float a = 0.f, b = 0.f;
#pragma unroll
    for (int i = 0; i < 16; ++i) { a += red[i]; b += red[16 + i]; }
    part[blockIdx.x * 2 + 0] = a;
    part[blockIdx.x * 2 + 1] = b;
  }
}

__global__ void finalize2_kernel(const float* __restrict__ part,
                                 float* __restrict__ out) {
  if (threadIdx.x == 0) {
    float a = 0.f, b = 0.f;
#pragma unroll
    for (int i = 0; i < 16; ++i) { a += part[i * 2]; b += part[i * 2 + 1]; }
    const float ds = expf(-a * (1.f / (float)NN));
    const float cs = expf(-b * (1.f / (float)NN));
    out[0] = ds;
    out[1] = cs;
    out[2] = 0.5f * (ds + cs);
  }
}

extern "C" void kernel_launch(void* const* d_in, const int* in_sizes, int n_in,
                              void* d_out, int out_size, void* d_ws, size_t ws_size,
                              hipStream_t stream) {
  (void)in_sizes; (void)n_in; (void)out_size; (void)ws_size;
  const float* A1 = (const float*)d_in[0];
  const float* A2 = (const float*)d_in[1];
  float* out = (float*)d_out;

  // workspace layout:
  //   A8   [2][2048*2048] u8  : 8 MB
  //   A8T  [2][2048*2048] u8  : 8 MB
  //   tri  [2][2048] f32
  //   degp [2][2048][32] f32
  //   part [32] f32
  u8* A8 = (u8*)d_ws;
  u8* A8T = A8 + 2 * (size_t)NN * NN;
  float* tri = (float*)(A8T + 2 * (size_t)NN * NN);
  float* degp = tri + 2 * NN;
  float* part = degp + 2 * 32 * NN;

  prep_kernel<<<dim3(32, 32, 2), 256, 0, stream>>>(A1, A2, A8, A8T, degp, tri);
  gemm_tri_kernel<<<dim3(16, 16, 4), 256, 0, stream>>>(A8, A8T, tri);
  finalize1_kernel<<<16, 1024, 0, stream>>>(degp, tri, part);
  finalize2_kernel<<<1, 64, 0, stream>>>(part, out);
}